// Round 2
// baseline (3148.474 us; speedup 1.0000x reference)
//
#include <hip/hip_runtime.h>
#include <hip/hip_bf16.h>
#include <math.h>

// Problem constants
#define BB 128
#define TT 1024
#define DD 256
#define HH 256
#define MM (BB * TT)
#define NN3 768

typedef __attribute__((ext_vector_type(8))) short short8;
typedef __attribute__((ext_vector_type(4))) float f32x4;
typedef __attribute__((address_space(1))) unsigned int gu32;
typedef __attribute__((address_space(3))) unsigned int lu32;

static __device__ __forceinline__ float bf2f(unsigned int u16) {
    return __uint_as_float(u16 << 16);
}
// RNE
static __device__ __forceinline__ unsigned short f2bf(float f) {
    unsigned int u = __float_as_uint(f);
    unsigned int r = u + 0x7FFFu + ((u >> 16) & 1u);
    return (unsigned short)(r >> 16);
}
// round-half-up, 2 ops (per-step activations)
static __device__ __forceinline__ unsigned short f2bf_fast(float f) {
    return (unsigned short)((__float_as_uint(f) + 0x8000u) >> 16);
}

static __device__ __forceinline__ void barrier_lgkm() {
    asm volatile("s_waitcnt lgkmcnt(0)\n\ts_barrier" ::: "memory");
}
static __device__ __forceinline__ void barrier_full() {
    asm volatile("s_waitcnt vmcnt(0) lgkmcnt(0)\n\ts_barrier" ::: "memory");
}

// ---------------------------------------------------------------------------
// Kernel A: transpose+convert W -> Wb[768][256] bf16 (row n = gate*256+col,
// entries along k). One block per n-row.
// ---------------------------------------------------------------------------
__global__ __launch_bounds__(256) void wb_kernel(
    const float* __restrict__ Wz, const float* __restrict__ Wr,
    const float* __restrict__ Wh, unsigned short* __restrict__ Wb)
{
    int n = blockIdx.x;          // 0..767
    int g = n >> 8, col = n & 255;
    const float* W = (g == 0) ? Wz : (g == 1 ? Wr : Wh);
    int k = threadIdx.x;         // 0..255
    Wb[(size_t)n * 256 + k] = f2bf(W[(size_t)k * HH + col]);
}

// ---------------------------------------------------------------------------
// Kernel B: xproj via bf16 MFMA, M-major / batch-fragment restructure.
// C = x[131072x256] @ Wcat[256x768] + bias, emitted bf16 in the
// recurrence-native xw layout.
//
// m-fragment = (16 batches x 1 timestep): MFMA C row (kq*4+i) == batch-in-16,
// col (nq) == n-col-in-tile, so each lane's 4 outputs land at CONSECUTIVE
// xw addresses st*256 + kq*64 + nq*4 + {0..3} -> one coalesced uint2 store
// (wave writes 512 B contiguous). x is loaded ONCE (register-resident af),
// W subtiles streamed per-iteration from L2-hot Wb.
//
// Block: 256 thr (4 waves). Block = bid (16 batches) x 8 timesteps; wave wv
// owns timesteps t0+wv*2 .. +1. Grid: 1024 blocks (8 bid x 128 t-chunks).
// ---------------------------------------------------------------------------
__global__ __launch_bounds__(256)
__attribute__((amdgpu_waves_per_eu(2, 2)))
void xproj_mfma(
    const float* __restrict__ x, const unsigned short* __restrict__ Wb,
    const float* __restrict__ bz, const float* __restrict__ br,
    const float* __restrict__ bh, unsigned short* __restrict__ xw)
{
    const int tid  = threadIdx.x;
    const int lane = tid & 63;
    const int wv   = tid >> 6;
    const int nq   = lane & 15;
    const int kq   = lane >> 4;

    const int bid = blockIdx.x >> 7;          // 0..7
    const int t0  = (blockIdx.x & 127) * 8;   // 0..1016
    const int tw0 = t0 + wv * 2;

    // x fragments, register-resident: af[c][mi], 64 VGPRs.
    // A row (nq) = batch-in-16; k = c*32 + kq*8 .. +7.
    short8 af[8][2];
#pragma unroll
    for (int mi = 0; mi < 2; ++mi) {
        const float* xrow = &x[((size_t)(bid * 16 + nq) * 1024 + (tw0 + mi)) * 256];
#pragma unroll
        for (int c = 0; c < 8; ++c) {
            const float* xp = xrow + c * 32 + kq * 8;
            float4 f0 = *(const float4*)xp;
            float4 f1 = *(const float4*)(xp + 4);
            short8 a;
            a[0] = (short)f2bf(f0.x); a[1] = (short)f2bf(f0.y);
            a[2] = (short)f2bf(f0.z); a[3] = (short)f2bf(f0.w);
            a[4] = (short)f2bf(f1.x); a[5] = (short)f2bf(f1.y);
            a[6] = (short)f2bf(f1.z); a[7] = (short)f2bf(f1.w);
            af[c][mi] = a;
        }
    }

#pragma unroll
    for (int g = 0; g < 3; ++g) {
        const float* bias = (g == 0) ? bz : (g == 1 ? br : bh);
#pragma unroll 2
        for (int s = 0; s < 16; ++s) {
            const int st = g * 16 + s;   // == gate-tile index ti in xw layout
            short8 wf[8];
#pragma unroll
            for (int c = 0; c < 8; ++c)
                wf[c] = *(const short8*)&Wb[(size_t)(st * 16 + nq) * 256
                                            + c * 32 + kq * 8];
            const float bv = bias[s * 16 + nq];

            f32x4 acc0 = (f32x4){0.f, 0.f, 0.f, 0.f};
            f32x4 acc1 = (f32x4){0.f, 0.f, 0.f, 0.f};
#pragma unroll
            for (int c = 0; c < 8; ++c) {
                acc0 = __builtin_amdgcn_mfma_f32_16x16x32_bf16(af[c][0], wf[c], acc0, 0, 0, 0);
                acc1 = __builtin_amdgcn_mfma_f32_16x16x32_bf16(af[c][1], wf[c], acc1, 0, 0, 0);
            }

#pragma unroll
            for (int mi = 0; mi < 2; ++mi) {
                f32x4 a = (mi == 0) ? acc0 : acc1;
                unsigned int lo = (unsigned int)f2bf(a[0] + bv)
                                | ((unsigned int)f2bf(a[1] + bv) << 16);
                unsigned int hi = (unsigned int)f2bf(a[2] + bv)
                                | ((unsigned int)f2bf(a[3] + bv) << 16);
                uint2 val; val.x = lo; val.y = hi;
                *(uint2*)&xw[(size_t)((tw0 + mi) * 8 + bid) * 12288
                             + st * 256 + kq * 64 + nq * 4] = val;
            }
        }
    }
}

// ---------------------------------------------------------------------------
// Kernel C: persistent-register MFMA GRU recurrence.
// 8 blocks x 1024 threads (16 waves, 4/SIMD). LDS-throughput-bound; this
// round only splits the phase-B MFMA chain into 2 parity chains (halves the
// 8-deep dependent-MFMA exposure; +4 VGPRs).
// ---------------------------------------------------------------------------
__global__ __launch_bounds__(1024)
__attribute__((amdgpu_waves_per_eu(4, 4)))
void gru_rec_kernel(
    const unsigned short* __restrict__ xw,
    const float* __restrict__ Uz, const float* __restrict__ Ur,
    const float* __restrict__ Uh,
    float* __restrict__ out)
{
    __shared__ unsigned short xstage[2][12288];  // 2 x 24576 B
    __shared__ short hA[16][264];    // h bf16, stride 132 dw
    __shared__ short rhA[16][264];   // r*h bf16

    const int tid  = threadIdx.x;
    const int lane = tid & 63;
    const int wv   = tid >> 6;       // 0..15
    const int nq   = lane & 15;
    const int kq   = lane >> 4;
    const int bid  = blockIdx.x;
    const int col0 = wv * 16;        // this wave's 16-column tile

    // ---- persistent weight fragments: 3 gates x 8 k-chunks = 96 regs/lane ----
    short8 wz[8], wr[8], whv[8];
#pragma unroll
    for (int c = 0; c < 8; ++c) {
        short8 fz, fr, fh;
#pragma unroll
        for (int j = 0; j < 8; ++j) {
            size_t rowoff = (size_t)(c * 32 + kq * 8 + j) * HH + col0 + nq;
            fz[j] = (short)f2bf(Uz[rowoff]);
            fr[j] = (short)f2bf(Ur[rowoff]);
            fh[j] = (short)f2bf(Uh[rowoff]);
        }
        wz[c] = fz; wr[c] = fr; whv[c] = fh;
    }

    for (int idx = tid; idx < 16 * 264; idx += 1024) ((short*)hA)[idx] = 0;
    float hprev[4];
#pragma unroll
    for (int i = 0; i < 4; ++i) hprev[i] = 0.f;

    // staging: 24576 B per (t,bid); waves 0..11 load 2048 B each (2x16B/lane)
    auto stage = [&](int t, int buf) {
        if (wv < 12) {
            const char* gsrc = (const char*)(xw + (size_t)(t * 8 + bid) * 12288);
            char* lbase = (char*)&xstage[buf][0];
            int woff = wv * 2048;
#pragma unroll
            for (int ld = 0; ld < 2; ++ld) {
                int off = woff + ld * 1024;
                __builtin_amdgcn_global_load_lds(
                    (const gu32*)(gsrc + off + lane * 16),
                    (lu32*)(lbase + off), 16, 0, 0);
            }
        }
    };

    stage(0, 0);
    barrier_full();

    auto step = [&](int t, int par) {
        int tn2 = (t + 1 < TT) ? (t + 1) : (TT - 1);
        stage(tn2, par ^ 1);

        const unsigned short* xs = &xstage[par][0];

        // ---- phase A: acc init = x (z,r), then MFMA chains over h ----
        f32x4 accZ, accR;
        {
            uint2 uz = *(const uint2*)&xs[((0  + wv) * 64 + lane) * 4];
            uint2 ur = *(const uint2*)&xs[((16 + wv) * 64 + lane) * 4];
            accZ[0] = bf2f(uz.x & 0xffffu);
            accZ[1] = bf2f(uz.x >> 16);
            accZ[2] = bf2f(uz.y & 0xffffu);
            accZ[3] = bf2f(uz.y >> 16);
            accR[0] = bf2f(ur.x & 0xffffu);
            accR[1] = bf2f(ur.x >> 16);
            accR[2] = bf2f(ur.y & 0xffffu);
            accR[3] = bf2f(ur.y >> 16);
        }
#pragma unroll
        for (int c = 0; c < 8; ++c) {
            short8 af = *(const short8*)&hA[nq][c * 32 + kq * 8];
            accZ = __builtin_amdgcn_mfma_f32_16x16x32_bf16(af, wz[c], accZ, 0, 0, 0);
            accR = __builtin_amdgcn_mfma_f32_16x16x32_bf16(af, wr[c], accR, 0, 0, 0);
        }

        // r epilogue only (z deferred to phase B; accZ stays live)
#pragma unroll
        for (int i = 0; i < 4; ++i) {
            float r = __builtin_amdgcn_fmed3f(
                __builtin_fmaf(0.2f, accR[i], 0.5f), 0.f, 1.f);
            rhA[kq * 4 + i][col0 + nq] = (short)f2bf_fast(r * hprev[i]);
        }
        barrier_lgkm();

        // ---- phase B: accH init = xh, MFMA over r*h (2 parity chains),
        //      z + h epilogue ----
        f32x4 accH0, accH1;
        {
            uint2 u = *(const uint2*)&xs[((32 + wv) * 64 + lane) * 4];
            accH0[0] = bf2f(u.x & 0xffffu);
            accH0[1] = bf2f(u.x >> 16);
            accH0[2] = bf2f(u.y & 0xffffu);
            accH0[3] = bf2f(u.y >> 16);
            accH1 = (f32x4){0.f, 0.f, 0.f, 0.f};
        }
#pragma unroll
        for (int c = 0; c < 8; ++c) {
            short8 af = *(const short8*)&rhA[nq][c * 32 + kq * 8];
            if (c & 1)
                accH1 = __builtin_amdgcn_mfma_f32_16x16x32_bf16(af, whv[c], accH1, 0, 0, 0);
            else
                accH0 = __builtin_amdgcn_mfma_f32_16x16x32_bf16(af, whv[c], accH0, 0, 0, 0);
        }

#pragma unroll
        for (int i = 0; i < 4; ++i) {
            float z = __builtin_amdgcn_fmed3f(
                __builtin_fmaf(0.2f, accZ[i], 0.5f), 0.f, 1.f);
            float a = __builtin_amdgcn_fmed3f(accH0[i] + accH1[i], -12.f, 12.f);
            float e  = exp2f(a * 2.88539008f);          // e^(2a)
            float hh = __builtin_fmaf(-2.f, __builtin_amdgcn_rcpf(e + 1.f), 1.f);
            float hn = __builtin_fmaf(z, hprev[i] - hh, hh);
            hprev[i] = hn;
            hA[kq * 4 + i][col0 + nq] = (short)f2bf_fast(hn);
        }
        barrier_full();
    };

    for (int t = 0; t < TT; t += 2) {
        step(t, 0);
        step(t + 1, 1);
    }

#pragma unroll
    for (int i = 0; i < 4; ++i)
        out[(size_t)(bid * 16 + kq * 4 + i) * HH + col0 + nq] = hprev[i];
}

// ---------------------------------------------------------------------------
extern "C" void kernel_launch(void* const* d_in, const int* in_sizes, int n_in,
                              void* d_out, int out_size, void* d_ws, size_t ws_size,
                              hipStream_t stream) {
    const float* x  = (const float*)d_in[0];
    const float* Wz = (const float*)d_in[1];
    const float* Wr = (const float*)d_in[2];
    const float* Wh = (const float*)d_in[3];
    const float* Uz = (const float*)d_in[4];
    const float* Ur = (const float*)d_in[5];
    const float* Uh = (const float*)d_in[6];
    const float* bz = (const float*)d_in[7];
    const float* br = (const float*)d_in[8];
    const float* bh = (const float*)d_in[9];
    float* out = (float*)d_out;

    // workspace: [xw: 192 MiB bf16][Wb: 768*256 bf16 = 384 KiB]
    unsigned short* xw = (unsigned short*)d_ws;
    unsigned short* Wb =
        (unsigned short*)((char*)d_ws + (size_t)MM * NN3 * sizeof(unsigned short));

    wb_kernel<<<NN3, 256, 0, stream>>>(Wz, Wr, Wh, Wb);

    // 1024 blocks: 8 bid-groups x 128 t-chunks of 8 timesteps
    xproj_mfma<<<1024, 256, 0, stream>>>(x, Wb, bz, br, bh, xw);

    gru_rec_kernel<<<8, 1024, 0, stream>>>(xw, Uz, Ur, Uh, out);
}

// Round 3
// 2492.000 us; speedup vs baseline: 1.2634x; 1.2634x over previous
//
#include <hip/hip_runtime.h>
#include <hip/hip_bf16.h>
#include <math.h>

// Problem constants
#define BB 128
#define TT 1024
#define DD 256
#define HH 256
#define MM (BB * TT)
#define NN3 768

typedef __attribute__((ext_vector_type(8))) short short8;
typedef __attribute__((ext_vector_type(4))) float f32x4;
typedef __attribute__((address_space(1))) unsigned int gu32;
typedef __attribute__((address_space(3))) unsigned int lu32;

static __device__ __forceinline__ float bf2f(unsigned int u16) {
    return __uint_as_float(u16 << 16);
}
// RNE
static __device__ __forceinline__ unsigned short f2bf(float f) {
    unsigned int u = __float_as_uint(f);
    unsigned int r = u + 0x7FFFu + ((u >> 16) & 1u);
    return (unsigned short)(r >> 16);
}
// round-half-up, 2 ops (per-step activations)
static __device__ __forceinline__ unsigned short f2bf_fast(float f) {
    return (unsigned short)((__float_as_uint(f) + 0x8000u) >> 16);
}

static __device__ __forceinline__ void barrier_lgkm() {
    asm volatile("s_waitcnt lgkmcnt(0)\n\ts_barrier" ::: "memory");
}
static __device__ __forceinline__ void barrier_full() {
    asm volatile("s_waitcnt vmcnt(0) lgkmcnt(0)\n\ts_barrier" ::: "memory");
}

// ---------------------------------------------------------------------------
// Kernel A: transpose+convert W -> Wb[768][256] bf16 (row n = gate*256+col,
// entries along k). One block per n-row.
// ---------------------------------------------------------------------------
__global__ __launch_bounds__(256) void wb_kernel(
    const float* __restrict__ Wz, const float* __restrict__ Wr,
    const float* __restrict__ Wh, unsigned short* __restrict__ Wb)
{
    int n = blockIdx.x;          // 0..767
    int g = n >> 8, col = n & 255;
    const float* W = (g == 0) ? Wz : (g == 1 ? Wr : Wh);
    int k = threadIdx.x;         // 0..255
    Wb[(size_t)n * 256 + k] = f2bf(W[(size_t)k * HH + col]);
}

// ---------------------------------------------------------------------------
// Kernel B: xproj via bf16 MFMA, M-major / batch-fragment restructure.
// C = x[131072x256] @ Wcat[256x768] + bias, emitted bf16 in the
// recurrence-native xw layout.
//
// m-fragment = (16 batches x 1 timestep): MFMA C row (kq*4+i) == batch-in-16,
// col (nq) == n-col-in-tile, so each lane's 4 outputs land at CONSECUTIVE
// xw addresses st*256 + kq*64 + nq*4 + {0..3} -> one coalesced uint2 store
// (wave writes 512 B contiguous). x is loaded ONCE (register-resident af),
// W subtiles streamed per-iteration from L2-hot Wb.
//
// Block: 256 thr (4 waves). Block = bid (16 batches) x 8 timesteps; wave wv
// owns timesteps t0+wv*2 .. +1. Grid: 1024 blocks (8 bid x 128 t-chunks).
// R3: waves_per_eu 2->4 (kernel is ~110 VGPR now; latency-bound, double TLP).
// ---------------------------------------------------------------------------
__global__ __launch_bounds__(256)
__attribute__((amdgpu_waves_per_eu(4, 4)))
void xproj_mfma(
    const float* __restrict__ x, const unsigned short* __restrict__ Wb,
    const float* __restrict__ bz, const float* __restrict__ br,
    const float* __restrict__ bh, unsigned short* __restrict__ xw)
{
    const int tid  = threadIdx.x;
    const int lane = tid & 63;
    const int wv   = tid >> 6;
    const int nq   = lane & 15;
    const int kq   = lane >> 4;

    const int bid = blockIdx.x >> 7;          // 0..7
    const int t0  = (blockIdx.x & 127) * 8;   // 0..1016
    const int tw0 = t0 + wv * 2;

    // x fragments, register-resident: af[c][mi], 64 VGPRs.
    // A row (nq) = batch-in-16; k = c*32 + kq*8 .. +7.
    short8 af[8][2];
#pragma unroll
    for (int mi = 0; mi < 2; ++mi) {
        const float* xrow = &x[((size_t)(bid * 16 + nq) * 1024 + (tw0 + mi)) * 256];
#pragma unroll
        for (int c = 0; c < 8; ++c) {
            const float* xp = xrow + c * 32 + kq * 8;
            float4 f0 = *(const float4*)xp;
            float4 f1 = *(const float4*)(xp + 4);
            short8 a;
            a[0] = (short)f2bf(f0.x); a[1] = (short)f2bf(f0.y);
            a[2] = (short)f2bf(f0.z); a[3] = (short)f2bf(f0.w);
            a[4] = (short)f2bf(f1.x); a[5] = (short)f2bf(f1.y);
            a[6] = (short)f2bf(f1.z); a[7] = (short)f2bf(f1.w);
            af[c][mi] = a;
        }
    }

#pragma unroll
    for (int g = 0; g < 3; ++g) {
        const float* bias = (g == 0) ? bz : (g == 1 ? br : bh);
#pragma unroll 2
        for (int s = 0; s < 16; ++s) {
            const int st = g * 16 + s;   // == gate-tile index ti in xw layout
            short8 wf[8];
#pragma unroll
            for (int c = 0; c < 8; ++c)
                wf[c] = *(const short8*)&Wb[(size_t)(st * 16 + nq) * 256
                                            + c * 32 + kq * 8];
            const float bv = bias[s * 16 + nq];

            f32x4 acc0 = (f32x4){0.f, 0.f, 0.f, 0.f};
            f32x4 acc1 = (f32x4){0.f, 0.f, 0.f, 0.f};
#pragma unroll
            for (int c = 0; c < 8; ++c) {
                acc0 = __builtin_amdgcn_mfma_f32_16x16x32_bf16(af[c][0], wf[c], acc0, 0, 0, 0);
                acc1 = __builtin_amdgcn_mfma_f32_16x16x32_bf16(af[c][1], wf[c], acc1, 0, 0, 0);
            }

#pragma unroll
            for (int mi = 0; mi < 2; ++mi) {
                f32x4 a = (mi == 0) ? acc0 : acc1;
                unsigned int lo = (unsigned int)f2bf(a[0] + bv)
                                | ((unsigned int)f2bf(a[1] + bv) << 16);
                unsigned int hi = (unsigned int)f2bf(a[2] + bv)
                                | ((unsigned int)f2bf(a[3] + bv) << 16);
                uint2 val; val.x = lo; val.y = hi;
                *(uint2*)&xw[(size_t)((tw0 + mi) * 8 + bid) * 12288
                             + st * 256 + kq * 64 + nq * 4] = val;
            }
        }
    }
}

// ---------------------------------------------------------------------------
// Kernel C: persistent-register MFMA GRU recurrence.
// 8 blocks x 1024 threads (16 waves, 4/SIMD).
// R3: phase-B parity split REVERTED to the R1-exact single accH chain —
// the split coincided with a 2208->2781 regression (MfmaUtil 0.92->0.73,
// all other counters identical); isolating whether it was the cause.
// ---------------------------------------------------------------------------
__global__ __launch_bounds__(1024)
__attribute__((amdgpu_waves_per_eu(4, 4)))
void gru_rec_kernel(
    const unsigned short* __restrict__ xw,
    const float* __restrict__ Uz, const float* __restrict__ Ur,
    const float* __restrict__ Uh,
    float* __restrict__ out)
{
    __shared__ unsigned short xstage[2][12288];  // 2 x 24576 B
    __shared__ short hA[16][264];    // h bf16, stride 132 dw
    __shared__ short rhA[16][264];   // r*h bf16

    const int tid  = threadIdx.x;
    const int lane = tid & 63;
    const int wv   = tid >> 6;       // 0..15
    const int nq   = lane & 15;
    const int kq   = lane >> 4;
    const int bid  = blockIdx.x;
    const int col0 = wv * 16;        // this wave's 16-column tile

    // ---- persistent weight fragments: 3 gates x 8 k-chunks = 96 regs/lane ----
    short8 wz[8], wr[8], whv[8];
#pragma unroll
    for (int c = 0; c < 8; ++c) {
        short8 fz, fr, fh;
#pragma unroll
        for (int j = 0; j < 8; ++j) {
            size_t rowoff = (size_t)(c * 32 + kq * 8 + j) * HH + col0 + nq;
            fz[j] = (short)f2bf(Uz[rowoff]);
            fr[j] = (short)f2bf(Ur[rowoff]);
            fh[j] = (short)f2bf(Uh[rowoff]);
        }
        wz[c] = fz; wr[c] = fr; whv[c] = fh;
    }

    for (int idx = tid; idx < 16 * 264; idx += 1024) ((short*)hA)[idx] = 0;
    float hprev[4];
#pragma unroll
    for (int i = 0; i < 4; ++i) hprev[i] = 0.f;

    // staging: 24576 B per (t,bid); waves 0..11 load 2048 B each (2x16B/lane)
    auto stage = [&](int t, int buf) {
        if (wv < 12) {
            const char* gsrc = (const char*)(xw + (size_t)(t * 8 + bid) * 12288);
            char* lbase = (char*)&xstage[buf][0];
            int woff = wv * 2048;
#pragma unroll
            for (int ld = 0; ld < 2; ++ld) {
                int off = woff + ld * 1024;
                __builtin_amdgcn_global_load_lds(
                    (const gu32*)(gsrc + off + lane * 16),
                    (lu32*)(lbase + off), 16, 0, 0);
            }
        }
    };

    stage(0, 0);
    barrier_full();

    auto step = [&](int t, int par) {
        int tn2 = (t + 1 < TT) ? (t + 1) : (TT - 1);
        stage(tn2, par ^ 1);

        const unsigned short* xs = &xstage[par][0];

        // ---- phase A: acc init = x (z,r), then MFMA chains over h ----
        f32x4 accZ, accR;
        {
            uint2 uz = *(const uint2*)&xs[((0  + wv) * 64 + lane) * 4];
            uint2 ur = *(const uint2*)&xs[((16 + wv) * 64 + lane) * 4];
            accZ[0] = bf2f(uz.x & 0xffffu);
            accZ[1] = bf2f(uz.x >> 16);
            accZ[2] = bf2f(uz.y & 0xffffu);
            accZ[3] = bf2f(uz.y >> 16);
            accR[0] = bf2f(ur.x & 0xffffu);
            accR[1] = bf2f(ur.x >> 16);
            accR[2] = bf2f(ur.y & 0xffffu);
            accR[3] = bf2f(ur.y >> 16);
        }
#pragma unroll
        for (int c = 0; c < 8; ++c) {
            short8 af = *(const short8*)&hA[nq][c * 32 + kq * 8];
            accZ = __builtin_amdgcn_mfma_f32_16x16x32_bf16(af, wz[c], accZ, 0, 0, 0);
            accR = __builtin_amdgcn_mfma_f32_16x16x32_bf16(af, wr[c], accR, 0, 0, 0);
        }

        // r epilogue only (z deferred to phase B; accZ stays live)
#pragma unroll
        for (int i = 0; i < 4; ++i) {
            float r = __builtin_amdgcn_fmed3f(
                __builtin_fmaf(0.2f, accR[i], 0.5f), 0.f, 1.f);
            rhA[kq * 4 + i][col0 + nq] = (short)f2bf_fast(r * hprev[i]);
        }
        barrier_lgkm();

        // ---- phase B: accH init = xh, MFMA over r*h, z + h epilogue ----
        f32x4 accH;
        {
            uint2 u = *(const uint2*)&xs[((32 + wv) * 64 + lane) * 4];
            accH[0] = bf2f(u.x & 0xffffu);
            accH[1] = bf2f(u.x >> 16);
            accH[2] = bf2f(u.y & 0xffffu);
            accH[3] = bf2f(u.y >> 16);
        }
#pragma unroll
        for (int c = 0; c < 8; ++c) {
            short8 af = *(const short8*)&rhA[nq][c * 32 + kq * 8];
            accH = __builtin_amdgcn_mfma_f32_16x16x32_bf16(af, whv[c], accH, 0, 0, 0);
        }

#pragma unroll
        for (int i = 0; i < 4; ++i) {
            float z = __builtin_amdgcn_fmed3f(
                __builtin_fmaf(0.2f, accZ[i], 0.5f), 0.f, 1.f);
            float a = __builtin_amdgcn_fmed3f(accH[i], -12.f, 12.f);
            float e  = exp2f(a * 2.88539008f);          // e^(2a)
            float hh = __builtin_fmaf(-2.f, __builtin_amdgcn_rcpf(e + 1.f), 1.f);
            float hn = __builtin_fmaf(z, hprev[i] - hh, hh);
            hprev[i] = hn;
            hA[kq * 4 + i][col0 + nq] = (short)f2bf_fast(hn);
        }
        barrier_full();
    };

    for (int t = 0; t < TT; t += 2) {
        step(t, 0);
        step(t + 1, 1);
    }

#pragma unroll
    for (int i = 0; i < 4; ++i)
        out[(size_t)(bid * 16 + kq * 4 + i) * HH + col0 + nq] = hprev[i];
}

// ---------------------------------------------------------------------------
extern "C" void kernel_launch(void* const* d_in, const int* in_sizes, int n_in,
                              void* d_out, int out_size, void* d_ws, size_t ws_size,
                              hipStream_t stream) {
    const float* x  = (const float*)d_in[0];
    const float* Wz = (const float*)d_in[1];
    const float* Wr = (const float*)d_in[2];
    const float* Wh = (const float*)d_in[3];
    const float* Uz = (const float*)d_in[4];
    const float* Ur = (const float*)d_in[5];
    const float* Uh = (const float*)d_in[6];
    const float* bz = (const float*)d_in[7];
    const float* br = (const float*)d_in[8];
    const float* bh = (const float*)d_in[9];
    float* out = (float*)d_out;

    // workspace: [xw: 192 MiB bf16][Wb: 768*256 bf16 = 384 KiB]
    unsigned short* xw = (unsigned short*)d_ws;
    unsigned short* Wb =
        (unsigned short*)((char*)d_ws + (size_t)MM * NN3 * sizeof(unsigned short));

    wb_kernel<<<NN3, 256, 0, stream>>>(Wz, Wr, Wh, Wb);

    // 1024 blocks: 8 bid-groups x 128 t-chunks of 8 timesteps
    xproj_mfma<<<1024, 256, 0, stream>>>(x, Wb, bz, br, bh, xw);

    gru_rec_kernel<<<8, 1024, 0, stream>>>(xw, Uz, Ur, Uh, out);
}